// Round 1
// baseline (419.699 us; speedup 1.0000x reference)
//
#include <hip/hip_runtime.h>

// ExemplarNoAttention: logits[b,c] = log( sum_{e: label[e]==c} exp(-beta*d2[b,e]) + eps )
// d2[b,e] = ||x_b||^2 + ||e_e||^2 - 2<x_b,e_e>, clamped >= 0; beta = softplus(beta_raw).
//
// Strategy: fp16 MFMA (16x16x32) for the 1024x50000x64 dot products, fused epilogue
// (exp + LDS-histogram segment-sum), never materializing sims. All data L2-resident.

#define NB      1024
#define NE      50000
#define NE_PAD  50176    // 49 chunks * 1024
#define KD      64
#define NC      10

using half8   = __attribute__((ext_vector_type(8))) _Float16;  // one MFMA A/B frag (4 VGPRs)
using half4v  = __attribute__((ext_vector_type(4))) _Float16;
using floatx4 = __attribute__((ext_vector_type(4))) float;

__device__ __forceinline__ float softplus_f(float x) {
  return (x > 20.f) ? x : log1pf(__expf(x));
}

// ---------------------------------------------------------------------------
// prep: convert x/exemplars to fp16, compute cb = -beta*||x||^2, ce = -beta*||e||^2.
// 16 lanes per row (float4 per lane -> 256B coalesced read, 8B half4 write),
// 4 rows per wave, 16 rows per block. Pad rows [NE, NE_PAD) get ce = -1e30 (sim=0).
// Also zeroes the class_sims accumulator (1024x10).
// ---------------------------------------------------------------------------
__global__ __launch_bounds__(256) void prep_kernel(
    const float* __restrict__ x, const float* __restrict__ ex,
    const float* __restrict__ beta_raw,
    _Float16* __restrict__ ex_h, float* __restrict__ ce,
    _Float16* __restrict__ x_h, float* __restrict__ cb,
    float* __restrict__ class_sims)
{
  const int tid = threadIdx.x;
  const int gid = blockIdx.x * 256 + tid;
  if (gid < NB * NC) class_sims[gid] = 0.f;

  const float beta = softplus_f(beta_raw[0]);

  const int row = blockIdx.x * 16 + (tid >> 4);  // grid covers NE_PAD + NB rows exactly
  const int l16 = tid & 15;

  if (row < NE_PAD) {
    float4 v = make_float4(0.f, 0.f, 0.f, 0.f);
    if (row < NE) v = ((const float4*)ex)[row * 16 + l16];
    half4v hv = { (_Float16)v.x, (_Float16)v.y, (_Float16)v.z, (_Float16)v.w };
    *(half4v*)(ex_h + (size_t)row * KD + l16 * 4) = hv;
    float s = v.x*v.x + v.y*v.y + v.z*v.z + v.w*v.w;
    #pragma unroll
    for (int m = 1; m < 16; m <<= 1) s += __shfl_xor(s, m, 64);
    if (l16 == 0) ce[row] = (row < NE) ? (-beta * s) : -1e30f;
  } else {
    const int rx = row - NE_PAD;  // [0, NB)
    float4 v = ((const float4*)x)[rx * 16 + l16];
    half4v hv = { (_Float16)v.x, (_Float16)v.y, (_Float16)v.z, (_Float16)v.w };
    *(half4v*)(x_h + (size_t)rx * KD + l16 * 4) = hv;
    float s = v.x*v.x + v.y*v.y + v.z*v.z + v.w*v.w;
    #pragma unroll
    for (int m = 1; m < 16; m <<= 1) s += __shfl_xor(s, m, 64);
    if (l16 == 0) cb[rx] = -beta * s;
  }
}

// ---------------------------------------------------------------------------
// main: grid = (16 b-tiles of 64 rows, 49 e-chunks of 1024). Block = 4 waves.
// Wave w owns batch rows [btile + 16w, btile + 16w + 16) (A-frags loaded once).
// MFMA mapping: M = batch (A = x), N = exemplar (B = ex rows, k-contiguous).
// C/D: col = lane&15 = exemplar, row = quad*4+r = batch row -> each lane's 4
// sims share one exemplar => one label load per 4 sims. Accumulate into LDS
// histogram part[64 rows][10 classes] via ds_add_f32; one global flush per block.
// ---------------------------------------------------------------------------
__global__ __launch_bounds__(256) void main_kernel(
    const _Float16* __restrict__ ex_h, const float* __restrict__ ce,
    const _Float16* __restrict__ x_h, const float* __restrict__ cb,
    const int* __restrict__ labels, const float* __restrict__ beta_raw,
    float* __restrict__ class_sims)
{
  __shared__ float part[64 * NC];
  const int tid = threadIdx.x;
  for (int i = tid; i < 64 * NC; i += 256) part[i] = 0.f;

  const int wave = tid >> 6;
  const int lane = tid & 63;
  const int l15  = lane & 15;
  const int quad = lane >> 4;

  const int btile = blockIdx.x * 64;   // gridDim.x = 16
  const int e0    = blockIdx.y * 1024; // gridDim.y = 49
  const int bm    = btile + wave * 16;

  const float beta = softplus_f(beta_raw[0]);
  const float s2 = 2.f * beta;

  // A-frags: x rows, lane l15 holds row bm+l15, k = quad*8 + {0..7} and +32.
  const half8* xrow = (const half8*)(x_h + (size_t)(bm + l15) * KD);
  const half8 a0 = xrow[quad];
  const half8 a1 = xrow[quad + 4];

  // cb for this lane's 4 output rows (bm + quad*4 + r)
  const float4 cb4 = ((const float4*)(cb + bm))[quad];
  const float cbq[4] = { cb4.x, cb4.y, cb4.z, cb4.w };

  __syncthreads();

  for (int s = 0; s < 64; ++s) {
    const int e = e0 + s * 16 + l15;
    const half8* erow = (const half8*)(ex_h + (size_t)e * KD);
    const half8 b0 = erow[quad];
    const half8 b1 = erow[quad + 4];
    const float cel = ce[e];
    const int lbl = labels[min(e, NE - 1)];  // pad rows: ce=-1e30 -> p=0, class 0 gets +0

    floatx4 d = {0.f, 0.f, 0.f, 0.f};
    d = __builtin_amdgcn_mfma_f32_16x16x32_f16(a0, b0, d, 0, 0, 0);
    d = __builtin_amdgcn_mfma_f32_16x16x32_f16(a1, b1, d, 0, 0, 0);

    const int rowbase = wave * 16 + quad * 4;
    #pragma unroll
    for (int r = 0; r < 4; ++r) {
      float t = fmaf(s2, d[r], cbq[r] + cel);  // -beta*d2 (before clamp)
      t = fminf(t, 0.f);                       // d2 = max(d2, 0)
      const float p = __expf(t);
      atomicAdd(&part[(rowbase + r) * NC + lbl], p);
    }
  }
  __syncthreads();

  for (int i = tid; i < 64 * NC; i += 256) {
    const int row = i / NC, c = i % NC;
    atomicAdd(&class_sims[(btile + row) * NC + c], part[i]);
  }
}

// ---------------------------------------------------------------------------
// finalize: logits = GAMMA(=1) * log(class_sims + eps)
// ---------------------------------------------------------------------------
__global__ __launch_bounds__(256) void log_kernel(
    const float* __restrict__ cs, float* __restrict__ out)
{
  const int i = blockIdx.x * 256 + threadIdx.x;
  if (i < NB * NC) out[i] = __logf(cs[i] + 1e-12f);
}

extern "C" void kernel_launch(void* const* d_in, const int* in_sizes, int n_in,
                              void* d_out, int out_size, void* d_ws, size_t ws_size,
                              hipStream_t stream)
{
  const float* x        = (const float*)d_in[0];
  const float* ex       = (const float*)d_in[1];
  const int*   labels   = (const int*)d_in[2];
  const float* beta_raw = (const float*)d_in[3];
  float* out = (float*)d_out;

  // Workspace layout (~6.8 MB total):
  char* ws = (char*)d_ws;
  _Float16* ex_h       = (_Float16*)ws;             // 50176*64*2 = 6,422,528 B
  float*    ce         = (float*)(ws + 6422528);    //   200,704 B
  _Float16* x_h        = (_Float16*)(ws + 6623232); //   131,072 B
  float*    cb         = (float*)(ws + 6754304);    //     4,096 B
  float*    class_sims = (float*)(ws + 6758400);    //    40,960 B  (end: 6,799,360)

  prep_kernel<<<3200, 256, 0, stream>>>(x, ex, beta_raw, ex_h, ce, x_h, cb, class_sims);
  dim3 g(16, 49);
  main_kernel<<<g, 256, 0, stream>>>(ex_h, ce, x_h, cb, labels, beta_raw, class_sims);
  log_kernel<<<40, 256, 0, stream>>>(class_sims, out);
}

// Round 3
// 147.689 us; speedup vs baseline: 2.8418x; 2.8418x over previous
//
#include <hip/hip_runtime.h>

// ExemplarNoAttention: logits[b,c] = log( sum_{e: label[e]==c} exp(-beta*d2[b,e]) + eps )
// d2[b,e] = ||x_b||^2 + ||e_e||^2 - 2<x_b,e_e>, clamped >= 0; beta = softplus(beta_raw).
//
// Round 2 strategy: transposed fp16 MFMA (D1[e,b] = ex . x^T) so the exp'd sims tile
// is directly the B-operand of a second 16x16x16 f16 MFMA against a onehot-label
// A-operand -> the 10-class segment-sum is accumulated in AGPRs with ZERO atomics
// in the inner loop (round 1 died on LDS fp32 atomicAdd CAS loops: 4300 cyc/iter,
// VALUBusy 3.8%). One native global fp32 atomic per (b,c) cell per block at the end.

#define NB      1024
#define NE      50000
#define NE_PAD  50176    // 98 chunks * 512
#define KD      64
#define NC      10

using half8   = __attribute__((ext_vector_type(8))) _Float16;  // 16x16x32 A/B frag (4 VGPRs)
using half4v  = __attribute__((ext_vector_type(4))) _Float16;  // 16x16x16 A/B frag (2 VGPRs)
using floatx4 = __attribute__((ext_vector_type(4))) float;

__device__ __forceinline__ float softplus_f(float x) {
  return (x > 20.f) ? x : log1pf(__expf(x));
}

// ---------------------------------------------------------------------------
// prep: cast x/exemplars to fp16, cb = -beta*||x||^2, ce = -beta*||e||^2,
// padded label copy (so main can read int4 up to NE_PAD), zero class_sims.
// 16 lanes per row (float4/lane), 16 rows per block. Pad rows get ce=-1e30 -> sim 0.
// ---------------------------------------------------------------------------
__global__ __launch_bounds__(256) void prep_kernel(
    const float* __restrict__ x, const float* __restrict__ ex,
    const int* __restrict__ labels, const float* __restrict__ beta_raw,
    _Float16* __restrict__ ex_h, float* __restrict__ ce,
    _Float16* __restrict__ x_h, float* __restrict__ cb,
    float* __restrict__ class_sims, int* __restrict__ lab_pad)
{
  const int tid = threadIdx.x;
  const int gid = blockIdx.x * 256 + tid;
  if (gid < NB * NC) class_sims[gid] = 0.f;

  const float beta = softplus_f(beta_raw[0]);

  const int row = blockIdx.x * 16 + (tid >> 4);  // 3200 blocks cover NE_PAD + NB rows
  const int l16 = tid & 15;

  if (row < NE_PAD) {
    float4 v = make_float4(0.f, 0.f, 0.f, 0.f);
    if (row < NE) v = ((const float4*)ex)[row * 16 + l16];
    half4v hv = { (_Float16)v.x, (_Float16)v.y, (_Float16)v.z, (_Float16)v.w };
    *(half4v*)(ex_h + (size_t)row * KD + l16 * 4) = hv;
    float s = v.x*v.x + v.y*v.y + v.z*v.z + v.w*v.w;
    #pragma unroll
    for (int m = 1; m < 16; m <<= 1) s += __shfl_xor(s, m, 64);
    if (l16 == 0) ce[row] = (row < NE) ? (-beta * s) : -1e30f;
    if (l16 == 1) lab_pad[row] = (row < NE) ? labels[row] : 0;
  } else {
    const int rx = row - NE_PAD;  // [0, NB)
    float4 v = ((const float4*)x)[rx * 16 + l16];
    half4v hv = { (_Float16)v.x, (_Float16)v.y, (_Float16)v.z, (_Float16)v.w };
    *(half4v*)(x_h + (size_t)rx * KD + l16 * 4) = hv;
    float s = v.x*v.x + v.y*v.y + v.z*v.z + v.w*v.w;
    #pragma unroll
    for (int m = 1; m < 16; m <<= 1) s += __shfl_xor(s, m, 64);
    if (l16 == 0) cb[rx] = -beta * s;
  }
}

// ---------------------------------------------------------------------------
// main: grid = (16 b-tiles of 64, 98 e-chunks of 512). Block = 4 waves, no LDS.
// Wave w owns batch cols [btile+16w, btile+16w+16); x B-frags loaded once.
// MFMA1 (16x16x32): D1[e=quad*4+r][b=l15] = <ex_e, x_b>.
// Epilogue: p = exp(min(2*beta*dot + cb + ce, 0)) -> fp16 (4 halfs = exactly the
//   B-operand frag of 16x16x16: B[k=quad*4+j][n=l15]).
// MFMA2 (16x16x16): acc[c=quad*4+r][b=l15] += onehot[c][e] . p[e][b],
//   onehot A-frag built from 4 label compares (lane's class = l15).
// Flush: one global fp32 atomic per (b, c<10) cell.
// ---------------------------------------------------------------------------
__global__ __launch_bounds__(256) void main_kernel(
    const _Float16* __restrict__ ex_h, const float* __restrict__ ce,
    const _Float16* __restrict__ x_h, const float* __restrict__ cb,
    const int* __restrict__ lab_pad, const float* __restrict__ beta_raw,
    float* __restrict__ class_sims)
{
  const int tid  = threadIdx.x;
  const int wave = tid >> 6;
  const int lane = tid & 63;
  const int l15  = lane & 15;
  const int quad = lane >> 4;

  const int bm = blockIdx.x * 64 + wave * 16;  // this wave's 16 batch columns
  const int e0 = blockIdx.y * 512;

  const float beta = softplus_f(beta_raw[0]);
  const float s2 = 2.f * beta;

  // x B-frags: B[k][n=l15] with k = quad*8+j (and +32) -> x row-major, loaded once.
  const half8* xrow = (const half8*)(x_h + (size_t)(bm + l15) * KD);
  const half8 bx0 = xrow[quad];
  const half8 bx1 = xrow[quad + 4];
  const float cbl = cb[bm + l15];

  floatx4 acc = {0.f, 0.f, 0.f, 0.f};

  #pragma unroll 2
  for (int s = 0; s < 32; ++s) {
    const int ebase = e0 + s * 16;
    // exemplar A-frags: A[m=l15][k=quad*8+j] -> ex row-major.
    const half8* erow = (const half8*)(ex_h + (size_t)(ebase + l15) * KD);
    const half8 ae0 = erow[quad];
    const half8 ae1 = erow[quad + 4];
    // per-quad broadcasts: ce and labels for this quad's 4 exemplar rows.
    const float4 ce4 = ((const float4*)(ce + ebase))[quad];
    const int4  lb4 = ((const int4*)(lab_pad + ebase))[quad];

    floatx4 d = {0.f, 0.f, 0.f, 0.f};
    d = __builtin_amdgcn_mfma_f32_16x16x32_f16(ae0, bx0, d, 0, 0, 0);
    d = __builtin_amdgcn_mfma_f32_16x16x32_f16(ae1, bx1, d, 0, 0, 0);

    const float cef[4] = { ce4.x, ce4.y, ce4.z, ce4.w };
    half4v p;
    #pragma unroll
    for (int r = 0; r < 4; ++r) {
      const float t = fminf(fmaf(s2, d[r], cbl + cef[r]), 0.f);  // -beta*max(d2,0)
      p[r] = (_Float16)__expf(t);
    }

    half4v oh;
    oh[0] = (lb4.x == l15) ? (_Float16)1.f : (_Float16)0.f;
    oh[1] = (lb4.y == l15) ? (_Float16)1.f : (_Float16)0.f;
    oh[2] = (lb4.z == l15) ? (_Float16)1.f : (_Float16)0.f;
    oh[3] = (lb4.w == l15) ? (_Float16)1.f : (_Float16)0.f;

    acc = __builtin_amdgcn_mfma_f32_16x16x16f16(oh, p, acc, 0, 0, 0);
  }

  // acc: lane holds class_part[c = quad*4+r][b = l15]
  #pragma unroll
  for (int r = 0; r < 4; ++r) {
    const int c = quad * 4 + r;
    if (c < NC) {
      __hip_atomic_fetch_add(&class_sims[(size_t)(bm + l15) * NC + c], acc[r],
                             __ATOMIC_RELAXED, __HIP_MEMORY_SCOPE_AGENT);
    }
  }
}

// ---------------------------------------------------------------------------
// finalize: logits = log(class_sims + eps)
// ---------------------------------------------------------------------------
__global__ __launch_bounds__(256) void log_kernel(
    const float* __restrict__ cs, float* __restrict__ out)
{
  const int i = blockIdx.x * 256 + threadIdx.x;
  if (i < NB * NC) out[i] = __logf(cs[i] + 1e-12f);
}

extern "C" void kernel_launch(void* const* d_in, const int* in_sizes, int n_in,
                              void* d_out, int out_size, void* d_ws, size_t ws_size,
                              hipStream_t stream)
{
  const float* x        = (const float*)d_in[0];
  const float* ex       = (const float*)d_in[1];
  const int*   labels   = (const int*)d_in[2];
  const float* beta_raw = (const float*)d_in[3];
  float* out = (float*)d_out;

  // Workspace layout (~7.0 MB total):
  char* ws = (char*)d_ws;
  _Float16* ex_h       = (_Float16*)ws;             // 50176*64*2 = 6,422,528 B
  float*    ce         = (float*)(ws + 6422528);    //   200,704 B
  _Float16* x_h        = (_Float16*)(ws + 6623232); //   131,072 B
  float*    cb         = (float*)(ws + 6754304);    //     4,096 B
  float*    class_sims = (float*)(ws + 6758400);    //    40,960 B
  int*      lab_pad    = (int*)(ws + 6799360);      //   200,704 B  (end: 7,000,064)

  prep_kernel<<<3200, 256, 0, stream>>>(x, ex, labels, beta_raw,
                                        ex_h, ce, x_h, cb, class_sims, lab_pad);
  dim3 g(16, 98);
  main_kernel<<<g, 256, 0, stream>>>(ex_h, ce, x_h, cb, lab_pad, beta_raw, class_sims);
  log_kernel<<<40, 256, 0, stream>>>(class_sims, out);
}